// Round 11
// baseline (376.802 us; speedup 1.0000x reference)
//
#include <hip/hip_runtime.h>
#include <hip/hip_bf16.h>

typedef __attribute__((ext_vector_type(8))) short bh8;
typedef __attribute__((ext_vector_type(4))) float fx4;
typedef __attribute__((ext_vector_type(8))) int i32x8;
typedef __attribute__((ext_vector_type(4))) int i32x4;

typedef const __attribute__((address_space(1))) unsigned int* gas_p;
typedef __attribute__((address_space(3))) unsigned int* las_p;

#define MFMA(a, b, c) __builtin_amdgcn_mfma_f32_16x16x32_bf16((a), (b), (c), 0, 0, 0)
// MX-scaled fp8 MFMA, K=128, unit scales (E8M0 127 -> 2^0): plain fp8 numerics at 2x rate
#define MFMAS(a, b, c) __builtin_amdgcn_mfma_scale_f32_16x16x128_f8f6f4( \
    (a), (b), (c), 0, 0, 0, 0x7f7f7f7f, 0, 0x7f7f7f7f)

__device__ __forceinline__ unsigned short f2bf(float f) {
  unsigned u = __builtin_bit_cast(unsigned, f);
  u += 0x7fff + ((u >> 16) & 1);   // RTNE
  return (unsigned short)(u >> 16);
}

__device__ __forceinline__ float bflo2f(unsigned u) { return __builtin_bit_cast(float, u << 16); }

__device__ __forceinline__ void gld16(const void* g, void* l) {
  __builtin_amdgcn_global_load_lds((gas_p)g, (las_p)l, 16, 0, 0);
}

// ---------------- weight transpose: w1[128,512]->w1t[512,128] bf16, w2[512,128]->w2t[128,512] bf16
__global__ __launch_bounds__(256) void transpose_weights(const float* __restrict__ w1,
                                                         const float* __restrict__ w2,
                                                         unsigned short* __restrict__ w1t,
                                                         unsigned short* __restrict__ w2t) {
  const int tgl = blockIdx.x * 256 + threadIdx.x;  // 0..65535
  { const int h = tgl >> 7, d = tgl & 127; w1t[tgl] = f2bf(w1[d * 512 + h]); }
  { const int d = tgl >> 9, h = tgl & 511; w2t[tgl] = f2bf(w2[h * 128 + d]); }
}

// ---------------- LN over D=128 + fp8 cast + FRAGMENT-MAJOR transpose.
// htf fragment f = gkt*32 + cg  (gkt = k/128, cg = col/16), 2 KB each:
//   htf[f][l*32 + j] = LN(x)[col = cg*16 + (l&15)][k = gkt*128 + (l>>4)*32 + j]
__global__ __launch_bounds__(256) void ln1_transpose(const float* __restrict__ x,
                                                     unsigned char* __restrict__ htf) {
  const int t = threadIdx.x, lane = t & 63, w = t >> 6;
  const int mt = blockIdx.x, b = blockIdx.y;
  __shared__ unsigned short tile[128 * 64];  // [d][m-chunk swizzled], bf16 staging
  const float* xb = x + ((size_t)b * 8192 + (size_t)mt * 64) * 128;
  for (int it = 0; it < 16; ++it) {
    const int r = w * 16 + it;  // local row 0..63
    const float2 v = *(const float2*)(xb + r * 128 + lane * 2);
    float s = v.x + v.y, s2 = v.x * v.x + v.y * v.y;
    #pragma unroll
    for (int o = 1; o < 64; o <<= 1) { s += __shfl_xor(s, o); s2 += __shfl_xor(s2, o); }
    const float mean = s * 0.0078125f;
    const float var = s2 * 0.0078125f - mean * mean;
    const float rstd = rsqrtf(var + 1e-5f);
    const int mc = r >> 3, ml = r & 7;
    const int d0 = lane * 2, d1 = d0 + 1;
    tile[d0 * 64 + ((mc ^ (d0 & 7)) << 3) + ml] = f2bf((v.x - mean) * rstd);
    tile[d1 * 64 + ((mc ^ (d1 & 7)) << 3) + ml] = f2bf((v.y - mean) * rstd);
  }
  __syncthreads();
  #pragma unroll
  for (int i = 0; i < 4; ++i) {
    const int idx = i * 256 + t;
    const int d = idx >> 3, mc = idx & 7;
    const bh8 vv = *(const bh8*)(tile + d * 64 + ((mc ^ (d & 7)) << 3));
    int lo = 0, hi = 0;
    lo = __builtin_amdgcn_cvt_pk_fp8_f32(bflo2f((unsigned short)vv[0]),
                                         bflo2f((unsigned short)vv[1]), lo, false);
    lo = __builtin_amdgcn_cvt_pk_fp8_f32(bflo2f((unsigned short)vv[2]),
                                         bflo2f((unsigned short)vv[3]), lo, true);
    hi = __builtin_amdgcn_cvt_pk_fp8_f32(bflo2f((unsigned short)vv[4]),
                                         bflo2f((unsigned short)vv[5]), hi, false);
    hi = __builtin_amdgcn_cvt_pk_fp8_f32(bflo2f((unsigned short)vv[6]),
                                         bflo2f((unsigned short)vv[7]), hi, true);
    const int col = b * 128 + d;
    const int k0 = mt * 64 + mc * 8;
    const int frag = (k0 >> 7) * 32 + (col >> 4);
    const int off = ((col & 15) + 16 * ((k0 >> 5) & 3)) * 32 + (k0 & 31);
    *(uint2*)(htf + (size_t)frag * 2048 + off) = (uint2){(unsigned)lo, (unsigned)hi};
  }
}

// ---------------- fused exp-softmax + attn GEMM: COALESCED adj stream, 2-deep prefetch.
// U[n,col] = sum_m exp(adj[n,m])*htf;  S[n] = sum_m exp(adj[n,m]).
// BM=64, BN=512, BK=128, split-K z=4, grid (128,4)=512 blocks -> 2 blocks/CU.
// 256 threads = 4 waves x 128 cols.  Al double-buffered (2x8 KB).  Two raw-adj register
// sets (a4a/a4b, loop unrolled x2).  Per tile t (ONE barrier):
//   ldA(cur buf); issue adj(t+2)->nxt; expCvt(t+1) [counted vmcnt: t+2 stays in flight];
//   writeA(other buf); MFMA with fragment-major B direct from L2; lgkmcnt; barrier.
// adj instr = 16 rows x 64 B contiguous (16 txns); each batch has ~1.5 tiles of cover;
// 2 blocks/CU x 2 tiles x 32 KB = 128 KB in flight per CU.
__global__ __launch_bounds__(256, 2) void fused_attn(const float* __restrict__ adj,
                                                     const unsigned char* __restrict__ htf,
                                                     unsigned short* __restrict__ pbuf,
                                                     float* __restrict__ sden) {
  const int tid = threadIdx.x, lane = tid & 63, wn = tid >> 6;
  const int mt = blockIdx.x, z = blockIdx.y;
  const int kbase = z * 2048;

  __shared__ unsigned char Al0[64 * 128];
  __shared__ unsigned char Al1[64 * 128];

  fx4 acc[4][8];
  #pragma unroll
  for (int i = 0; i < 4; ++i)
    #pragma unroll
    for (int j = 0; j < 8; ++j) acc[i][j] = (fx4){0.f, 0.f, 0.f, 0.f};

  i32x8 afr[4];

  // A path: thread owns row ar = tid>>2, lane-quarter aq = tid&3.
  // Load j: floats [j*16 + aq*4 .. +4) of the row  ->  coalesced 64 B per row per instr.
  const int ar = tid >> 2, aq = tid & 3;
  const float* aroot = adj + (size_t)(mt * 64 + ar) * 8192 + kbase;
  float sacc = 0.f;
  float4 a4a[8], a4b[8];
  unsigned pk[8];

  auto issueAdj = [&](float4 (&dst)[8], int tau) {
    #pragma unroll
    for (int j = 0; j < 8; ++j)
      dst[j] = *(const float4*)(aroot + tau * 128 + j * 16 + aq * 4);
  };
  auto expCvt = [&](const float4 (&src)[8]) {
    #pragma unroll
    for (int j = 0; j < 8; ++j) {
      const float e0 = __expf(src[j].x), e1 = __expf(src[j].y);
      const float e2 = __expf(src[j].z), e3 = __expf(src[j].w);
      sacc += (e0 + e1) + (e2 + e3);
      int d = 0;
      d = __builtin_amdgcn_cvt_pk_fp8_f32(e0, e1, d, false);
      d = __builtin_amdgcn_cvt_pk_fp8_f32(e2, e3, d, true);
      pk[j] = (unsigned)d;
    }
  };
  auto writeA = [&](unsigned char* buf) {
    // pk[j] = 4 fp8 for k = j*16 + aq*4 : granule j (phys j^(ar&7)), byte-in-granule aq*4
    #pragma unroll
    for (int j = 0; j < 8; ++j)
      *(unsigned*)&buf[ar * 128 + ((j ^ (ar & 7)) << 4) + aq * 4] = pk[j];
  };
  auto ldAall = [&](const unsigned char* buf) {
    #pragma unroll
    for (int mf = 0; mf < 4; ++mf) {
      const int rr = mf * 16 + (lane & 15);
      const int gb = (lane >> 4) * 2;
      const unsigned char* base = &buf[rr * 128];
      const i32x4 lo = *(const i32x4*)(base + ((gb ^ (rr & 7)) << 4));
      const i32x4 hi = *(const i32x4*)(base + (((gb + 1) ^ (rr & 7)) << 4));
      afr[mf] = (i32x8){lo.x, lo.y, lo.z, lo.w, hi.x, hi.y, hi.z, hi.w};
    }
  };
  auto mfmaPhase = [&](int tt) {
    const int gkt = z * 16 + tt;
    const unsigned char* fb = htf + ((size_t)gkt * 32 + wn * 8) * 2048 + lane * 32;
    #pragma unroll
    for (int nf = 0; nf < 8; ++nf) {
      const unsigned char* fp = fb + nf * 2048;
      const i32x4 blo = *(const i32x4*)(fp);
      const i32x4 bhi = *(const i32x4*)(fp + 16);
      const i32x8 bfr = (i32x8){blo.x, blo.y, blo.z, blo.w, bhi.x, bhi.y, bhi.z, bhi.w};
      #pragma unroll
      for (int mf = 0; mf < 4; ++mf)
        acc[mf][nf] = MFMAS(afr[mf], bfr, acc[mf][nf]);
    }
  };
  auto body = [&](int tt, unsigned char* bufCur, unsigned char* bufNxt,
                  float4 (&cur)[8], float4 (&nxt)[8]) {
    ldAall(bufCur);                       // ds_read, lgkm-waited by compiler before MFMA
    if (tt + 2 < 16) issueAdj(nxt, tt + 2);
    if (tt + 1 < 16) {
      expCvt(cur);                        // counted vmcnt: waits cur only, nxt in flight
      writeA(bufNxt);
    }
    mfmaPhase(tt);
    asm volatile("s_waitcnt lgkmcnt(0)" ::: "memory");  // my ds reads+writes done
    __builtin_amdgcn_sched_barrier(0);
    __builtin_amdgcn_s_barrier();         // bufNxt visible / bufCur free for overwrite
    __builtin_amdgcn_sched_barrier(0);
  };

  // ---- prologue: tile0 -> Al0, tile1 raw -> a4a ----
  issueAdj(a4a, 0);
  expCvt(a4a);        // vmcnt wait (one-time prologue stall)
  writeA(Al0);
  issueAdj(a4a, 1);   // a4a registers free after expCvt; reload with tile1
  asm volatile("s_waitcnt lgkmcnt(0)" ::: "memory");
  __builtin_amdgcn_sched_barrier(0);
  __builtin_amdgcn_s_barrier();
  __builtin_amdgcn_sched_barrier(0);

  // ---- 16 K-tiles, unrolled x2 for static a4a/a4b indexing ----
  for (int i = 0; i < 8; ++i) {
    const int t0 = 2 * i;
    body(t0, Al0, Al1, a4a, a4b);   // reads Al0; tile t0+1 exp -> Al1; issue t0+2 -> a4b
    body(t0 + 1, Al1, Al0, a4b, a4a);
  }

  // ---- denominator: reduce quarter partials within each row-quad ----
  sacc += __shfl_xor(sacc, 1);
  sacc += __shfl_xor(sacc, 2);
  if (aq == 0) sden[(size_t)z * 8192 + mt * 64 + ar] = sacc;

  // ---- store unnormalized partial U as bf16: pbuf[z][row n][col b*128+d] ----
  unsigned short* po = pbuf + (size_t)z * 8192 * 512;
  #pragma unroll
  for (int mf = 0; mf < 4; ++mf)
    #pragma unroll
    for (int nf = 0; nf < 8; ++nf) {
      const int col = wn * 128 + nf * 16 + (lane & 15);
      #pragma unroll
      for (int q = 0; q < 4; ++q) {
        const int row = mt * 64 + mf * 16 + (lane >> 4) * 4 + q;
        po[(size_t)row * 512 + col] = f2bf(acc[mf][nf][q]);
      }
    }
}

// ---------------- fused LN2 + FFN: x1 = x + (sum_z U_z)/(sum_z S_z); h1 = LN(x1) -> As;
// out = x1 + relu(h1@w1+b1)@w2 + b2.  x1 parked f32 in As/W1c LDS after their last read.
#define SWZ16(ks, r) (((((ks) & 7) ^ ((r) & 7)) | ((ks) & 8)))
__global__ __launch_bounds__(512) void ln_ffn_kernel(const float* __restrict__ x,
                                                     const unsigned short* __restrict__ pbuf,
                                                     const float* __restrict__ sden,
                                                     const unsigned short* __restrict__ w1t,
                                                     const unsigned short* __restrict__ w2t,
                                                     const float* __restrict__ b1,
                                                     const float* __restrict__ b2,
                                                     float* __restrict__ out) {
  const int t = threadIdx.x, lane = t & 63, w = t >> 6;
  const int wr = w >> 1, wc = w & 1;   // 8 waves: 4x32 rows, 2x64 cols
  const int row0 = blockIdx.x * 128;
  __shared__ unsigned short As[128 * 128];
  __shared__ unsigned short W1c[128 * 128];
  __shared__ unsigned short W2c[128 * 128];
  __shared__ unsigned short Ts[128 * 128];

  auto stageW1 = [&](int hc) {
    #pragma unroll
    for (int i = 0; i < 4; ++i) {
      const int idx = i * 512 + t;
      const int row = idx >> 4, kc = idx & 15;
      const int kcs = (kc & 8) | ((kc & 7) ^ (row & 7));
      gld16(w1t + (size_t)(hc * 128 + row) * 128 + kcs * 8, W1c + (idx & ~63) * 8);
    }
  };
  auto stageW2 = [&](int hc) {
    #pragma unroll
    for (int i = 0; i < 4; ++i) {
      const int idx = i * 512 + t;
      const int row = idx >> 4, kc = idx & 15;
      const int kcs = (kc & 8) | ((kc & 7) ^ (row & 7));
      gld16(w2t + (size_t)row * 512 + hc * 128 + kcs * 8, W2c + (idx & ~63) * 8);
    }
  };

  stageW1(0); stageW2(0);

  // x1 = x + (sum U)/(sum S); LN over D=128 (4 threads/row); h1 -> As (bf16, swizzled)
  const int r = t >> 2, q = t & 3, c0 = q * 32;
  const int rowg = row0 + r;
  const int bb = rowg >> 13, nn = rowg & 8191;
  float xv[32];
  {
    const float den = sden[nn] + sden[8192 + nn] + sden[16384 + nn] + sden[24576 + nn];
    const float rinv = 1.f / den;
    const float* xp = x + (size_t)rowg * 128 + c0;
    #pragma unroll
    for (int j = 0; j < 8; ++j) {
      const float4 v4 = *(const float4*)(xp + 4 * j);
      xv[4 * j] = v4.x; xv[4 * j + 1] = v4.y; xv[4 * j + 2] = v4.z; xv[4 * j + 3] = v4.w;
    }
    #pragma unroll
    for (int z = 0; z < 4; ++z) {
      const unsigned short* pp = pbuf + ((size_t)z * 8192 + nn) * 512 + bb * 128 + c0;
      #pragma unroll
      for (int j = 0; j < 4; ++j) {
        const bh8 pv = *(const bh8*)(pp + 8 * j);
        #pragma unroll
        for (int e = 0; e < 8; ++e) xv[8 * j + e] += bflo2f((unsigned short)pv[e]) * rinv;
      }
    }
  }
  float s = 0.f, s2 = 0.f;
  #pragma unroll
  for (int j = 0; j < 32; ++j) { s += xv[j]; s2 += xv[j] * xv[j]; }
  s += __shfl_xor(s, 1); s2 += __shfl_xor(s2, 1);
  s += __shfl_xor(s, 2); s2 += __shfl_xor(s2, 2);
  const float mean = s * 0.0078125f;
  const float var = s2 * 0.0078125f - mean * mean;
  const float rstd = rsqrtf(var + 1e-5f);
  #pragma unroll
  for (int j = 0; j < 4; ++j) {
    const int g = q * 4 + j;
    bh8 pk;
    #pragma unroll
    for (int e = 0; e < 8; ++e) pk[e] = (short)f2bf((xv[8 * j + e] - mean) * rstd);
    *(bh8*)(As + r * 128 + SWZ16(g, r) * 8) = pk;
  }
  __syncthreads();  // As ready; W(0) staged

  fx4 accO[2][4];
  #pragma unroll
  for (int i = 0; i < 2; ++i)
    #pragma unroll
    for (int j = 0; j < 4; ++j) accO[i][j] = (fx4){0.f, 0.f, 0.f, 0.f};

  for (int hc = 0; hc < 4; ++hc) {
    if (hc > 0) stageW2(hc);  // overlaps GEMM1; drained at post-Ts barrier
    fx4 accT[2][4];
    #pragma unroll
    for (int i = 0; i < 2; ++i)
      #pragma unroll
      for (int j = 0; j < 4; ++j) accT[i][j] = (fx4){0.f, 0.f, 0.f, 0.f};
    #pragma unroll
    for (int kk = 0; kk < 4; ++kk) {
      const int ks = kk * 4 + (lane >> 4);
      bh8 af[2], bfr[4];
      #pragma unroll
      for (int f = 0; f < 2; ++f) {
        const int ra = wr * 32 + f * 16 + (lane & 15);
        af[f] = *(const bh8*)(As + ra * 128 + SWZ16(ks, ra) * 8);
      }
      #pragma unroll
      for (int f = 0; f < 4; ++f) {
        const int rb = wc * 64 + f * 16 + (lane & 15);
        bfr[f] = *(const bh8*)(W1c + rb * 128 + SWZ16(ks, rb) * 8);
      }
      #pragma unroll
      for (int fm = 0; fm < 2; ++fm)
        #pragma unroll
        for (int fn = 0; fn < 4; ++fn) accT[fm][fn] = MFMA(af[fm], bfr[fn], accT[fm][fn]);
    }
    // bias + relu -> Ts (bf16, swizzled)
    #pragma unroll
    for (int fm = 0; fm < 2; ++fm)
      #pragma unroll
      for (int fn = 0; fn < 4; ++fn) {
        const int col = wc * 64 + fn * 16 + (lane & 15);
        const float bv = b1[hc * 128 + col];
        const int c = col >> 3;
        #pragma unroll
        for (int qq = 0; qq < 4; ++qq) {
          const int row = wr * 32 + fm * 16 + (lane >> 4) * 4 + qq;
          float vv = accT[fm][fn][qq] + bv;
          vv = fmaxf(vv, 0.f);
          Ts[row * 128 + SWZ16(c, row) * 8 + (col & 7)] = f2bf(vv);
        }
      }
    __syncthreads();  // Ts ready; As/W1c GEMM1 reads done; W2c(hc) landed
    if (hc < 3) {
      stageW1(hc + 1);  // overlaps GEMM2; drained at loop-end barrier
    } else {
      // park x1 (f32) into As (rows 0-63) / W1c (rows 64-127) — both dead now
      float* dst = (r < 64) ? (float*)As + r * 128 + c0 : (float*)W1c + (r - 64) * 128 + c0;
      #pragma unroll
      for (int j = 0; j < 8; ++j)
        *(float4*)(dst + 4 * j) =
            (float4){xv[4 * j], xv[4 * j + 1], xv[4 * j + 2], xv[4 * j + 3]};
    }
    #pragma unroll
    for (int kk = 0; kk < 4; ++kk) {
      const int ks = kk * 4 + (lane >> 4);
      bh8 af[2], bfr[4];
      #pragma unroll
      for (int f = 0; f < 2; ++f) {
        const int ra = wr * 32 + f * 16 + (lane & 15);
        af[f] = *(const bh8*)(Ts + ra * 128 + SWZ16(ks, ra) * 8);
      }
      #pragma unroll
      for (int f = 0; f < 4; ++f) {
        const int rb = wc * 64 + f * 16 + (lane & 15);
        bfr[f] = *(const bh8*)(W2c + rb * 128 + SWZ16(ks, rb) * 8);
      }
      #pragma unroll
      for (int fm = 0; fm < 2; ++fm)
        #pragma unroll
        for (int fn = 0; fn < 4; ++fn) accO[fm][fn] = MFMA(af[fm], bfr[fn], accO[fm][fn]);
    }
    __syncthreads();
  }

  const float* x1a = (const float*)As;
  const float* x1b = (const float*)W1c;
  float* op = out + (size_t)row0 * 128;
  #pragma unroll
  for (int fm = 0; fm < 2; ++fm)
    #pragma unroll
    for (int fn = 0; fn < 4; ++fn) {
      const int col = wc * 64 + fn * 16 + (lane & 15);
      const float bv = b2[col];
      #pragma unroll
      for (int qq = 0; qq < 4; ++qq) {
        const int row = wr * 32 + fm * 16 + (lane >> 4) * 4 + qq;
        const float x1v = (row < 64) ? x1a[row * 128 + col] : x1b[(row - 64) * 128 + col];
        op[row * 128 + col] = x1v + accO[fm][fn][qq] + bv;
      }
    }
}

extern "C" void kernel_launch(void* const* d_in, const int* in_sizes, int n_in,
                              void* d_out, int out_size, void* d_ws, size_t ws_size,
                              hipStream_t stream) {
  const float* x   = (const float*)d_in[0];
  const float* adj = (const float*)d_in[1];
  const float* w1  = (const float*)d_in[4];
  const float* b1  = (const float*)d_in[5];
  const float* w2  = (const float*)d_in[6];
  const float* b2  = (const float*)d_in[7];
  float* out = (float*)d_out;

  char* p = (char*)d_ws;
  unsigned short* w1t  = (unsigned short*)p; p += (size_t)512 * 128 * 2;
  unsigned short* w2t  = (unsigned short*)p; p += (size_t)128 * 512 * 2;
  unsigned char*  htf  = (unsigned char*)p;  p += (size_t)4 * 128 * 8192;
  unsigned short* pbuf = (unsigned short*)p; p += (size_t)4 * 8192 * 512 * 2;
  float*          sden = (float*)p;          p += (size_t)4 * 8192 * 4;

  transpose_weights<<<256, 256, 0, stream>>>(w1, w2, w1t, w2t);
  ln1_transpose<<<dim3(128, 4), 256, 0, stream>>>(x, htf);
  fused_attn<<<dim3(128, 4), 256, 0, stream>>>(adj, htf, pbuf, sden);
  ln_ffn_kernel<<<256, 512, 0, stream>>>(x, pbuf, sden, w1t, w2t, b1, b2, out);
}

// Round 12
// 150.537 us; speedup vs baseline: 2.5031x; 2.5031x over previous
//
#include <hip/hip_runtime.h>
#include <hip/hip_bf16.h>

typedef __attribute__((ext_vector_type(8))) short bh8;
typedef __attribute__((ext_vector_type(4))) float fx4;
typedef __attribute__((ext_vector_type(8))) int i32x8;
typedef __attribute__((ext_vector_type(4))) int i32x4;

typedef const __attribute__((address_space(1))) unsigned int* gas_p;
typedef __attribute__((address_space(3))) unsigned int* las_p;

#define MFMA(a, b, c) __builtin_amdgcn_mfma_f32_16x16x32_bf16((a), (b), (c), 0, 0, 0)
// MX-scaled fp8 MFMA, K=128, unit scales (E8M0 127 -> 2^0): plain fp8 numerics at 2x rate
#define MFMAS(a, b, c) __builtin_amdgcn_mfma_scale_f32_16x16x128_f8f6f4( \
    (a), (b), (c), 0, 0, 0, 0x7f7f7f7f, 0, 0x7f7f7f7f)

__device__ __forceinline__ unsigned short f2bf(float f) {
  unsigned u = __builtin_bit_cast(unsigned, f);
  u += 0x7fff + ((u >> 16) & 1);   // RTNE
  return (unsigned short)(u >> 16);
}

__device__ __forceinline__ float bflo2f(unsigned u) { return __builtin_bit_cast(float, u << 16); }

__device__ __forceinline__ void gld16(const void* g, void* l) {
  __builtin_amdgcn_global_load_lds((gas_p)g, (las_p)l, 16, 0, 0);
}

// ---------------- weight transpose: w1[128,512]->w1t[512,128] bf16, w2[512,128]->w2t[128,512] bf16
__global__ __launch_bounds__(256) void transpose_weights(const float* __restrict__ w1,
                                                         const float* __restrict__ w2,
                                                         unsigned short* __restrict__ w1t,
                                                         unsigned short* __restrict__ w2t) {
  const int tgl = blockIdx.x * 256 + threadIdx.x;  // 0..65535
  { const int h = tgl >> 7, d = tgl & 127; w1t[tgl] = f2bf(w1[d * 512 + h]); }
  { const int d = tgl >> 9, h = tgl & 511; w2t[tgl] = f2bf(w2[h * 128 + d]); }
}

// ---------------- LN over D=128 + transpose to ht[b*128+d][m] (fp8 e4m3) == B^T[512][8192]
__global__ __launch_bounds__(256) void ln1_transpose(const float* __restrict__ x,
                                                     unsigned char* __restrict__ ht) {
  const int t = threadIdx.x, lane = t & 63, w = t >> 6;
  const int mt = blockIdx.x, b = blockIdx.y;
  __shared__ unsigned short tile[128 * 64];  // [d][m-chunk swizzled], bf16 staging
  const float* xb = x + ((size_t)b * 8192 + (size_t)mt * 64) * 128;
  for (int it = 0; it < 16; ++it) {
    const int r = w * 16 + it;  // local row 0..63
    const float2 v = *(const float2*)(xb + r * 128 + lane * 2);
    float s = v.x + v.y, s2 = v.x * v.x + v.y * v.y;
    #pragma unroll
    for (int o = 1; o < 64; o <<= 1) { s += __shfl_xor(s, o); s2 += __shfl_xor(s2, o); }
    const float mean = s * 0.0078125f;
    const float var = s2 * 0.0078125f - mean * mean;
    const float rstd = rsqrtf(var + 1e-5f);
    const int mc = r >> 3, ml = r & 7;
    const int d0 = lane * 2, d1 = d0 + 1;
    tile[d0 * 64 + ((mc ^ (d0 & 7)) << 3) + ml] = f2bf((v.x - mean) * rstd);
    tile[d1 * 64 + ((mc ^ (d1 & 7)) << 3) + ml] = f2bf((v.y - mean) * rstd);
  }
  __syncthreads();
  unsigned char* hb = ht + (size_t)b * 128 * 8192 + (size_t)mt * 64;
  #pragma unroll
  for (int i = 0; i < 4; ++i) {
    const int idx = i * 256 + t;
    const int d = idx >> 3, mc = idx & 7;
    const bh8 vv = *(const bh8*)(tile + d * 64 + ((mc ^ (d & 7)) << 3));
    int lo = 0, hi = 0;
    lo = __builtin_amdgcn_cvt_pk_fp8_f32(bflo2f((unsigned short)vv[0]),
                                         bflo2f((unsigned short)vv[1]), lo, false);
    lo = __builtin_amdgcn_cvt_pk_fp8_f32(bflo2f((unsigned short)vv[2]),
                                         bflo2f((unsigned short)vv[3]), lo, true);
    hi = __builtin_amdgcn_cvt_pk_fp8_f32(bflo2f((unsigned short)vv[4]),
                                         bflo2f((unsigned short)vv[5]), hi, false);
    hi = __builtin_amdgcn_cvt_pk_fp8_f32(bflo2f((unsigned short)vv[6]),
                                         bflo2f((unsigned short)vv[7]), hi, true);
    *(uint2*)(hb + (size_t)d * 8192 + mc * 8) = (uint2){(unsigned)lo, (unsigned)hi};
  }
}

// ---------------- fused exp-softmax + attn GEMM, streaming, STAGED B, COALESCED adj.
// U[n,col] = sum_m exp(adj[n,m])*ht[col,m];  S[n] = sum_m exp(adj[n,m]).
// BM=64, BN=512, BK=128 (MX-fp8), split-K z=4, grid (128,4)=512 blocks -> 2 blocks/CU
// (LDS 8+64=72 KB).  256 threads = 4 waves, each owns 128 cols.  Per K-tile:
//   { ldA frags, issue adj(t+1) COALESCED (j*16+aq*4: 16 rows x 64 B/instr), MFMA from Bl }
//   barrier; { stageB(t+1) 16x gld16, expCvt (counted vmcnt: gld16 stay in flight),
//   writeA (8x ds_write_b32, 2-way bank = free) } vmcnt(0)+barrier.
__global__ __launch_bounds__(256, 2) void fused_attn(const float* __restrict__ adj,
                                                     const unsigned char* __restrict__ ht,
                                                     unsigned short* __restrict__ pbuf,
                                                     float* __restrict__ sden) {
  const int tid = threadIdx.x, lane = tid & 63, wn = tid >> 6;
  const int mt = blockIdx.x, z = blockIdx.y;
  const int kbase = z * 2048;

  __shared__ unsigned char Al[64 * 128];    // 8 KB, single-buffered
  __shared__ unsigned char Bl[512 * 128];   // 64 KB, single-buffered

  fx4 acc[4][8];
  #pragma unroll
  for (int i = 0; i < 4; ++i)
    #pragma unroll
    for (int j = 0; j < 8; ++j) acc[i][j] = (fx4){0.f, 0.f, 0.f, 0.f};

  i32x8 afr[4];

  // A path: thread owns row ar = tid>>2, lane-quarter aq = tid&3.
  // Load j = floats [j*16 + aq*4, +4): wave instr touches 16 rows x 64 B contiguous.
  const int ar = tid >> 2, aq = tid & 3;
  const float* aroot = adj + (size_t)(mt * 64 + ar) * 8192 + kbase;
  float sacc = 0.f;
  float4 a4[8];
  unsigned pk[8];

  auto issueAdj = [&](int tau) {
    #pragma unroll
    for (int j = 0; j < 8; ++j)
      a4[j] = *(const float4*)(aroot + tau * 128 + j * 16 + aq * 4);
  };
  auto expCvt = [&]() {
    #pragma unroll
    for (int j = 0; j < 8; ++j) {
      const float e0 = __expf(a4[j].x), e1 = __expf(a4[j].y);
      const float e2 = __expf(a4[j].z), e3 = __expf(a4[j].w);
      sacc += (e0 + e1) + (e2 + e3);
      int d = 0;
      d = __builtin_amdgcn_cvt_pk_fp8_f32(e0, e1, d, false);
      d = __builtin_amdgcn_cvt_pk_fp8_f32(e2, e3, d, true);
      pk[j] = (unsigned)d;
    }
  };
  auto writeA = [&]() {
    // pk[j] = 4 fp8 at k = j*16 + aq*4 -> granule j (phys j^(ar&7)), byte aq*4
    #pragma unroll
    for (int j = 0; j < 8; ++j)
      *(unsigned*)&Al[ar * 128 + ((j ^ (ar & 7)) << 4) + aq * 4] = pk[j];
  };
  auto stageB = [&](int tau) {
    #pragma unroll
    for (int j = 0; j < 16; ++j) {
      const int idx = j * 256 + tid;
      const int col = idx >> 3, g = idx & 7;
      gld16(ht + (size_t)col * 8192 + kbase + tau * 128 + ((g ^ (col & 7)) << 4),
            Bl + idx * 16);
    }
  };
  auto ldAall = [&]() {
    #pragma unroll
    for (int mf = 0; mf < 4; ++mf) {
      const int rr = mf * 16 + (lane & 15);
      const int gb = (lane >> 4) * 2;
      const unsigned char* base = &Al[rr * 128];
      const i32x4 lo = *(const i32x4*)(base + ((gb ^ (rr & 7)) << 4));
      const i32x4 hi = *(const i32x4*)(base + (((gb + 1) ^ (rr & 7)) << 4));
      afr[mf] = (i32x8){lo.x, lo.y, lo.z, lo.w, hi.x, hi.y, hi.z, hi.w};
    }
  };

  // ---- prologue: tile 0 ----
  issueAdj(0);
  expCvt();        // compiler waits vmcnt for a4
  writeA();
  stageB(0);       // 16 gld16
  asm volatile("s_waitcnt lgkmcnt(0) vmcnt(0)" ::: "memory");
  __builtin_amdgcn_sched_barrier(0);
  __builtin_amdgcn_s_barrier();
  __builtin_amdgcn_sched_barrier(0);

  // ---- 16 K-tiles ----
  for (int tt = 0; tt < 16; ++tt) {
    ldAall();
    if (tt < 15) issueAdj(tt + 1);   // oldest vmem: full MFMA phase of cover

    #pragma unroll
    for (int nf = 0; nf < 8; ++nf) {
      const int c = wn * 128 + nf * 16 + (lane & 15);
      const int gb = (lane >> 4) * 2;
      const unsigned char* cb = &Bl[c * 128];
      const i32x4 blo = *(const i32x4*)(cb + ((gb ^ (c & 7)) << 4));
      const i32x4 bhi = *(const i32x4*)(cb + (((gb + 1) ^ (c & 7)) << 4));
      const i32x8 bfr = (i32x8){blo.x, blo.y, blo.z, blo.w, bhi.x, bhi.y, bhi.z, bhi.w};
      #pragma unroll
      for (int mf = 0; mf < 4; ++mf)
        acc[mf][nf] = MFMAS(afr[mf], bfr, acc[mf][nf]);
    }

    asm volatile("s_waitcnt lgkmcnt(0)" ::: "memory");  // my Al/Bl reads done
    __builtin_amdgcn_sched_barrier(0);
    __builtin_amdgcn_s_barrier();    // all waves done reading -> LDS free
    __builtin_amdgcn_sched_barrier(0);

    if (tt < 15) {
      stageB(tt + 1);   // issue gld16 early; exp VALU covers L2 latency
      expCvt();         // counted vmcnt: waits adj only, gld16 stays in flight
      writeA();
      asm volatile("s_waitcnt lgkmcnt(0) vmcnt(0)" ::: "memory");
      __builtin_amdgcn_sched_barrier(0);
      __builtin_amdgcn_s_barrier();  // A+B for tile tt+1 visible
      __builtin_amdgcn_sched_barrier(0);
    }
  }

  // ---- denominator: reduce quarter partials within each row-quad ----
  sacc += __shfl_xor(sacc, 1);
  sacc += __shfl_xor(sacc, 2);
  if (aq == 0) sden[(size_t)z * 8192 + mt * 64 + ar] = sacc;

  // ---- store unnormalized partial U as bf16: pbuf[z][row n][col b*128+d] ----
  unsigned short* po = pbuf + (size_t)z * 8192 * 512;
  #pragma unroll
  for (int mf = 0; mf < 4; ++mf)
    #pragma unroll
    for (int nf = 0; nf < 8; ++nf) {
      const int col = wn * 128 + nf * 16 + (lane & 15);
      #pragma unroll
      for (int q = 0; q < 4; ++q) {
        const int row = mt * 64 + mf * 16 + (lane >> 4) * 4 + q;
        po[(size_t)row * 512 + col] = f2bf(acc[mf][nf][q]);
      }
    }
}

// ---------------- fused LN2 + FFN: x1 = x + (sum_z U_z)/(sum_z S_z); h1 = LN(x1) -> As;
// out = x1 + relu(h1@w1+b1)@w2 + b2.  x1 parked f32 in As/W1c LDS after their last read.
#define SWZ16(ks, r) (((((ks) & 7) ^ ((r) & 7)) | ((ks) & 8)))
__global__ __launch_bounds__(512) void ln_ffn_kernel(const float* __restrict__ x,
                                                     const unsigned short* __restrict__ pbuf,
                                                     const float* __restrict__ sden,
                                                     const unsigned short* __restrict__ w1t,
                                                     const unsigned short* __restrict__ w2t,
                                                     const float* __restrict__ b1,
                                                     const float* __restrict__ b2,
                                                     float* __restrict__ out) {
  const int t = threadIdx.x, lane = t & 63, w = t >> 6;
  const int wr = w >> 1, wc = w & 1;   // 8 waves: 4x32 rows, 2x64 cols
  const int row0 = blockIdx.x * 128;
  __shared__ unsigned short As[128 * 128];
  __shared__ unsigned short W1c[128 * 128];
  __shared__ unsigned short W2c[128 * 128];
  __shared__ unsigned short Ts[128 * 128];

  auto stageW1 = [&](int hc) {
    #pragma unroll
    for (int i = 0; i < 4; ++i) {
      const int idx = i * 512 + t;
      const int row = idx >> 4, kc = idx & 15;
      const int kcs = (kc & 8) | ((kc & 7) ^ (row & 7));
      gld16(w1t + (size_t)(hc * 128 + row) * 128 + kcs * 8, W1c + (idx & ~63) * 8);
    }
  };
  auto stageW2 = [&](int hc) {
    #pragma unroll
    for (int i = 0; i < 4; ++i) {
      const int idx = i * 512 + t;
      const int row = idx >> 4, kc = idx & 15;
      const int kcs = (kc & 8) | ((kc & 7) ^ (row & 7));
      gld16(w2t + (size_t)row * 512 + hc * 128 + kcs * 8, W2c + (idx & ~63) * 8);
    }
  };

  stageW1(0); stageW2(0);

  // x1 = x + (sum U)/(sum S); LN over D=128 (4 threads/row); h1 -> As (bf16, swizzled)
  const int r = t >> 2, q = t & 3, c0 = q * 32;
  const int rowg = row0 + r;
  const int bb = rowg >> 13, nn = rowg & 8191;
  float xv[32];
  {
    const float den = sden[nn] + sden[8192 + nn] + sden[16384 + nn] + sden[24576 + nn];
    const float rinv = 1.f / den;
    const float* xp = x + (size_t)rowg * 128 + c0;
    #pragma unroll
    for (int j = 0; j < 8; ++j) {
      const float4 v4 = *(const float4*)(xp + 4 * j);
      xv[4 * j] = v4.x; xv[4 * j + 1] = v4.y; xv[4 * j + 2] = v4.z; xv[4 * j + 3] = v4.w;
    }
    #pragma unroll
    for (int z = 0; z < 4; ++z) {
      const unsigned short* pp = pbuf + ((size_t)z * 8192 + nn) * 512 + bb * 128 + c0;
      #pragma unroll
      for (int j = 0; j < 4; ++j) {
        const bh8 pv = *(const bh8*)(pp + 8 * j);
        #pragma unroll
        for (int e = 0; e < 8; ++e) xv[8 * j + e] += bflo2f((unsigned short)pv[e]) * rinv;
      }
    }
  }
  float s = 0.f, s2 = 0.f;
  #pragma unroll
  for (int j = 0; j < 32; ++j) { s += xv[j]; s2 += xv[j] * xv[j]; }
  s += __shfl_xor(s, 1); s2 += __shfl_xor(s2, 1);
  s += __shfl_xor(s, 2); s2 += __shfl_xor(s2, 2);
  const float mean = s * 0.0078125f;
  const float var = s2 * 0.0078125f - mean * mean;
  const float rstd = rsqrtf(var + 1e-5f);
  #pragma unroll
  for (int j = 0; j < 4; ++j) {
    const int g = q * 4 + j;
    bh8 pk;
    #pragma unroll
    for (int e = 0; e < 8; ++e) pk[e] = (short)f2bf((xv[8 * j + e] - mean) * rstd);
    *(bh8*)(As + r * 128 + SWZ16(g, r) * 8) = pk;
  }
  __syncthreads();  // As ready; W(0) staged

  fx4 accO[2][4];
  #pragma unroll
  for (int i = 0; i < 2; ++i)
    #pragma unroll
    for (int j = 0; j < 4; ++j) accO[i][j] = (fx4){0.f, 0.f, 0.f, 0.f};

  for (int hc = 0; hc < 4; ++hc) {
    if (hc > 0) stageW2(hc);  // overlaps GEMM1; drained at post-Ts barrier
    fx4 accT[2][4];
    #pragma unroll
    for (int i = 0; i < 2; ++i)
      #pragma unroll
      for (int j = 0; j < 4; ++j) accT[i][j] = (fx4){0.f, 0.f, 0.f, 0.f};
    #pragma unroll
    for (int kk = 0; kk < 4; ++kk) {
      const int ks = kk * 4 + (lane >> 4);
      bh8 af[2], bfr[4];
      #pragma unroll
      for (int f = 0; f < 2; ++f) {
        const int ra = wr * 32 + f * 16 + (lane & 15);
        af[f] = *(const bh8*)(As + ra * 128 + SWZ16(ks, ra) * 8);
      }
      #pragma unroll
      for (int f = 0; f < 4; ++f) {
        const int rb = wc * 64 + f * 16 + (lane & 15);
        bfr[f] = *(const bh8*)(W1c + rb * 128 + SWZ16(ks, rb) * 8);
      }
      #pragma unroll
      for (int fm = 0; fm < 2; ++fm)
        #pragma unroll
        for (int fn = 0; fn < 4; ++fn) accT[fm][fn] = MFMA(af[fm], bfr[fn], accT[fm][fn]);
    }
    // bias + relu -> Ts (bf16, swizzled)
    #pragma unroll
    for (int fm = 0; fm < 2; ++fm)
      #pragma unroll
      for (int fn = 0; fn < 4; ++fn) {
        const int col = wc * 64 + fn * 16 + (lane & 15);
        const float bv = b1[hc * 128 + col];
        const int c = col >> 3;
        #pragma unroll
        for (int qq = 0; qq < 4; ++qq) {
          const int row = wr * 32 + fm * 16 + (lane >> 4) * 4 + qq;
          float vv = accT[fm][fn][qq] + bv;
          vv = fmaxf(vv, 0.f);
          Ts[row * 128 + SWZ16(c, row) * 8 + (col & 7)] = f2bf(vv);
        }
      }
    __syncthreads();  // Ts ready; As/W1c GEMM1 reads done; W2c(hc) landed
    if (hc < 3) {
      stageW1(hc + 1);  // overlaps GEMM2; drained at loop-end barrier
    } else {
      // park x1 (f32) into As (rows 0-63) / W1c (rows 64-127) — both dead now
      float* dst = (r < 64) ? (float*)As + r * 128 + c0 : (float*)W1c + (r - 64) * 128 + c0;
      #pragma unroll
      for (int j = 0; j < 8; ++j)
        *(float4*)(dst + 4 * j) =
            (float4){xv[4 * j], xv[4 * j + 1], xv[4 * j + 2], xv[4 * j + 3]};
    }
    #pragma unroll
    for (int kk = 0; kk < 4; ++kk) {
      const int ks = kk * 4 + (lane >> 4);
      bh8 af[2], bfr[4];
      #pragma unroll
      for (int f = 0; f < 2; ++f) {
        const int ra = wr * 32 + f * 16 + (lane & 15);
        af[f] = *(const bh8*)(Ts + ra * 128 + SWZ16(ks, ra) * 8);
      }
      #pragma unroll
      for (int f = 0; f < 4; ++f) {
        const int rb = wc * 64 + f * 16 + (lane & 15);
        bfr[f] = *(const bh8*)(W2c + rb * 128 + SWZ16(ks, rb) * 8);
      }
      #pragma unroll
      for (int fm = 0; fm < 2; ++fm)
        #pragma unroll
        for (int fn = 0; fn < 4; ++fn) accO[fm][fn] = MFMA(af[fm], bfr[fn], accO[fm][fn]);
    }
    __syncthreads();
  }

  const float* x1a = (const float*)As;
  const float* x1b = (const float*)W1c;
  float* op = out + (size_t)row0 * 128;
  #pragma unroll
  for (int fm = 0; fm < 2; ++fm)
    #pragma unroll
    for (int fn = 0; fn < 4; ++fn) {
      const int col = wc * 64 + fn * 16 + (lane & 15);
      const float bv = b2[col];
      #pragma unroll
      for (int qq = 0; qq < 4; ++qq) {
        const int row = wr * 32 + fm * 16 + (lane >> 4) * 4 + qq;
        const float x1v = (row < 64) ? x1a[row * 128 + col] : x1b[(row - 64) * 128 + col];
        op[row * 128 + col] = x1v + accO[fm][fn][qq] + bv;
      }
    }
}

extern "C" void kernel_launch(void* const* d_in, const int* in_sizes, int n_in,
                              void* d_out, int out_size, void* d_ws, size_t ws_size,
                              hipStream_t stream) {
  const float* x   = (const float*)d_in[0];
  const float* adj = (const float*)d_in[1];
  const float* w1  = (const float*)d_in[4];
  const float* b1  = (const float*)d_in[5];
  const float* w2  = (const float*)d_in[6];
  const float* b2  = (const float*)d_in[7];
  float* out = (float*)d_out;

  char* p = (char*)d_ws;
  unsigned short* w1t  = (unsigned short*)p; p += (size_t)512 * 128 * 2;
  unsigned short* w2t  = (unsigned short*)p; p += (size_t)128 * 512 * 2;
  unsigned char*  ht   = (unsigned char*)p;  p += (size_t)4 * 128 * 8192;
  unsigned short* pbuf = (unsigned short*)p; p += (size_t)4 * 8192 * 512 * 2;
  float*          sden = (float*)p;          p += (size_t)4 * 8192 * 4;

  transpose_weights<<<256, 256, 0, stream>>>(w1, w2, w1t, w2t);
  ln1_transpose<<<dim3(128, 4), 256, 0, stream>>>(x, ht);
  fused_attn<<<dim3(128, 4), 256, 0, stream>>>(adj, ht, pbuf, sden);
  ln_ffn_kernel<<<256, 512, 0, stream>>>(x, pbuf, sden, w1t, w2t, b1, b2, out);
}

// Round 13
// 150.199 us; speedup vs baseline: 2.5087x; 1.0022x over previous
//
#include <hip/hip_runtime.h>
#include <hip/hip_bf16.h>

typedef __attribute__((ext_vector_type(8))) short bh8;
typedef __attribute__((ext_vector_type(4))) float fx4;
typedef __attribute__((ext_vector_type(8))) int i32x8;
typedef __attribute__((ext_vector_type(4))) int i32x4;

typedef const __attribute__((address_space(1))) unsigned int* gas_p;
typedef __attribute__((address_space(3))) unsigned int* las_p;

#define MFMA(a, b, c) __builtin_amdgcn_mfma_f32_16x16x32_bf16((a), (b), (c), 0, 0, 0)
// MX-scaled fp8 MFMA, K=128, unit scales (E8M0 127 -> 2^0): plain fp8 numerics at 2x rate
#define MFMAS(a, b, c) __builtin_amdgcn_mfma_scale_f32_16x16x128_f8f6f4( \
    (a), (b), (c), 0, 0, 0, 0x7f7f7f7f, 0, 0x7f7f7f7f)

__device__ __forceinline__ unsigned short f2bf(float f) {
  unsigned u = __builtin_bit_cast(unsigned, f);
  u += 0x7fff + ((u >> 16) & 1);   // RTNE
  return (unsigned short)(u >> 16);
}

__device__ __forceinline__ float bflo2f(unsigned u) { return __builtin_bit_cast(float, u << 16); }

__device__ __forceinline__ void gld16(const void* g, void* l) {
  __builtin_amdgcn_global_load_lds((gas_p)g, (las_p)l, 16, 0, 0);
}

// ---------------- weight transpose: w1[128,512]->w1t[512,128] bf16, w2[512,128]->w2t[128,512] bf16
__global__ __launch_bounds__(256) void transpose_weights(const float* __restrict__ w1,
                                                         const float* __restrict__ w2,
                                                         unsigned short* __restrict__ w1t,
                                                         unsigned short* __restrict__ w2t) {
  const int tgl = blockIdx.x * 256 + threadIdx.x;  // 0..65535
  { const int h = tgl >> 7, d = tgl & 127; w1t[tgl] = f2bf(w1[d * 512 + h]); }
  { const int d = tgl >> 9, h = tgl & 511; w2t[tgl] = f2bf(w2[h * 128 + d]); }
}

// ---------------- LN over D=128 + fp8 cast + FRAGMENT-MAJOR transpose (r10 layout).
// htf fragment f = gkt*32 + cg  (gkt = k/128, cg = col/16), 2 KB each:
//   htf[f][l*32 + j] = LN(x)[col = cg*16 + (l&15)][k = gkt*128 + (l>>4)*32 + j]
__global__ __launch_bounds__(256) void ln1_transpose(const float* __restrict__ x,
                                                     unsigned char* __restrict__ htf) {
  const int t = threadIdx.x, lane = t & 63, w = t >> 6;
  const int mt = blockIdx.x, b = blockIdx.y;
  __shared__ unsigned short tile[128 * 64];  // [d][m-chunk swizzled], bf16 staging
  const float* xb = x + ((size_t)b * 8192 + (size_t)mt * 64) * 128;
  for (int it = 0; it < 16; ++it) {
    const int r = w * 16 + it;  // local row 0..63
    const float2 v = *(const float2*)(xb + r * 128 + lane * 2);
    float s = v.x + v.y, s2 = v.x * v.x + v.y * v.y;
    #pragma unroll
    for (int o = 1; o < 64; o <<= 1) { s += __shfl_xor(s, o); s2 += __shfl_xor(s2, o); }
    const float mean = s * 0.0078125f;
    const float var = s2 * 0.0078125f - mean * mean;
    const float rstd = rsqrtf(var + 1e-5f);
    const int mc = r >> 3, ml = r & 7;
    const int d0 = lane * 2, d1 = d0 + 1;
    tile[d0 * 64 + ((mc ^ (d0 & 7)) << 3) + ml] = f2bf((v.x - mean) * rstd);
    tile[d1 * 64 + ((mc ^ (d1 & 7)) << 3) + ml] = f2bf((v.y - mean) * rstd);
  }
  __syncthreads();
  #pragma unroll
  for (int i = 0; i < 4; ++i) {
    const int idx = i * 256 + t;
    const int d = idx >> 3, mc = idx & 7;
    const bh8 vv = *(const bh8*)(tile + d * 64 + ((mc ^ (d & 7)) << 3));
    int lo = 0, hi = 0;
    lo = __builtin_amdgcn_cvt_pk_fp8_f32(bflo2f((unsigned short)vv[0]),
                                         bflo2f((unsigned short)vv[1]), lo, false);
    lo = __builtin_amdgcn_cvt_pk_fp8_f32(bflo2f((unsigned short)vv[2]),
                                         bflo2f((unsigned short)vv[3]), lo, true);
    hi = __builtin_amdgcn_cvt_pk_fp8_f32(bflo2f((unsigned short)vv[4]),
                                         bflo2f((unsigned short)vv[5]), hi, false);
    hi = __builtin_amdgcn_cvt_pk_fp8_f32(bflo2f((unsigned short)vv[6]),
                                         bflo2f((unsigned short)vv[7]), hi, true);
    const int col = b * 128 + d;
    const int k0 = mt * 64 + mc * 8;
    const int frag = (k0 >> 7) * 32 + (col >> 4);
    const int off = ((col & 15) + 16 * ((k0 >> 5) & 3)) * 32 + (k0 & 31);
    *(uint2*)(htf + (size_t)frag * 2048 + off) = (uint2){(unsigned)lo, (unsigned)hi};
  }
}

// ---------------- fused exp-softmax + attn GEMM: adj DMA'd through LDS (deep pipeline).
// U[n,col] = sum_m exp(adj[n,m])*htf;  S[n] = sum_m exp(adj[n,m]).
// BM=64, BN=512, BK=128, split-K z=4, grid (128,4)=512 blocks.
// LDS: Ar[2] raw fp32 adj (2x32 KB, gld16-staged, XOR-granule layout via pre-swizzled src)
//    + Al[2] fp8 (2x8 KB) = 80 KB -> 2 blocks/CU.  256 threads = 4 waves x 128 cols.
// Per tile t (ONE barrier): issue DMA adj(t+2) [fire-and-forget]; ldA(Al[cur]); MFMA
// (B fragment-major direct from L2); vmcnt(8) [waits t+1 ONLY - issued a full tile ago];
// expCvt from Ar[cur^1]; writeA -> Al[cur^1]; lgkmcnt(0); barrier.
__global__ __launch_bounds__(256, 2) void fused_attn(const float* __restrict__ adj,
                                                     const unsigned char* __restrict__ htf,
                                                     unsigned short* __restrict__ pbuf,
                                                     float* __restrict__ sden) {
  const int tid = threadIdx.x, lane = tid & 63, wn = tid >> 6;
  const int mt = blockIdx.x, z = blockIdx.y;
  const int kbase = z * 2048;

  __shared__ float Ar[2][64 * 128];          // 2 x 32 KB raw adj
  __shared__ unsigned char Al[2][64 * 128];  // 2 x 8 KB fp8

  fx4 acc[4][8];
  #pragma unroll
  for (int i = 0; i < 4; ++i)
    #pragma unroll
    for (int j = 0; j < 8; ++j) acc[i][j] = (fx4){0.f, 0.f, 0.f, 0.f};

  i32x8 afr[4];

  const int ar = tid >> 2, aq = tid & 3;     // conversion role: row ar, k-quarter aq
  float sacc = 0.f;
  unsigned pk[8];

  // DMA one 32 KB raw tile: 8 calls x (256 threads x 16 B).  Dest linear (wave-uniform
  // base + lane*16); source pre-swizzled so phys granule p of row r holds logical p^(r&7).
  auto issueAr = [&](int buf, int tau) {
    const int l = tid & 63, wid = tid >> 6;
    #pragma unroll
    for (int c = 0; c < 8; ++c) {
      const int r = c * 8 + wid * 2 + (l >> 5);   // local row 0..63
      const int p = l & 31;                        // phys 16B-granule in row
      const float* src = adj + (size_t)(mt * 64 + r) * 8192 + kbase + tau * 128
                         + ((p ^ (r & 7)) << 2);
      gld16(src, (char*)&Ar[buf][0] + c * 4096 + wid * 1024);
    }
  };
  // exp+cvt tile from Ar[buf]: thread (ar,aq), j-th float4 = logical granule j*4+aq
  // (k = j*16 + aq*4 .. +4) at phys (j*4+aq)^(ar&7).  Same FP order as before.
  auto expCvt = [&](int buf) {
    #pragma unroll
    for (int j = 0; j < 8; ++j) {
      const int g = j * 4 + aq;
      const float4 v = *(const float4*)((const char*)&Ar[buf][0] + ar * 512 +
                                        ((g ^ (ar & 7)) << 4));
      const float e0 = __expf(v.x), e1 = __expf(v.y);
      const float e2 = __expf(v.z), e3 = __expf(v.w);
      sacc += (e0 + e1) + (e2 + e3);
      int d = 0;
      d = __builtin_amdgcn_cvt_pk_fp8_f32(e0, e1, d, false);
      d = __builtin_amdgcn_cvt_pk_fp8_f32(e2, e3, d, true);
      pk[j] = (unsigned)d;
    }
  };
  auto writeA = [&](int buf) {
    // pk[j] = 4 fp8 at k = j*16 + aq*4 -> fp8 granule j (phys j^(ar&7)), byte aq*4
    #pragma unroll
    for (int j = 0; j < 8; ++j)
      *(unsigned*)&Al[buf][ar * 128 + ((j ^ (ar & 7)) << 4) + aq * 4] = pk[j];
  };
  auto ldAall = [&](int buf) {
    #pragma unroll
    for (int mf = 0; mf < 4; ++mf) {
      const int rr = mf * 16 + (lane & 15);
      const int gb = (lane >> 4) * 2;
      const unsigned char* base = &Al[buf][rr * 128];
      const i32x4 lo = *(const i32x4*)(base + ((gb ^ (rr & 7)) << 4));
      const i32x4 hi = *(const i32x4*)(base + (((gb + 1) ^ (rr & 7)) << 4));
      afr[mf] = (i32x8){lo.x, lo.y, lo.z, lo.w, hi.x, hi.y, hi.z, hi.w};
    }
  };
  auto mfmaPhase = [&](int tt) {
    const int gkt = z * 16 + tt;
    const unsigned char* fb = htf + ((size_t)gkt * 32 + wn * 8) * 2048 + lane * 32;
    #pragma unroll
    for (int nf = 0; nf < 8; ++nf) {
      const unsigned char* fp = fb + nf * 2048;
      const i32x4 blo = *(const i32x4*)(fp);
      const i32x4 bhi = *(const i32x4*)(fp + 16);
      const i32x8 bfr = (i32x8){blo.x, blo.y, blo.z, blo.w, bhi.x, bhi.y, bhi.z, bhi.w};
      #pragma unroll
      for (int mf = 0; mf < 4; ++mf)
        acc[mf][nf] = MFMAS(afr[mf], bfr, acc[mf][nf]);
    }
  };
  auto body = [&](int tt, bool doIssue, bool doConv) {
    const int cur = tt & 1;
    if (doIssue) issueAr(cur, tt + 2);      // fire-and-forget DMA into just-freed buffer
    ldAall(cur);
    mfmaPhase(tt);                          // B consumed by compiler-inserted vmcnt
    if (doConv) {
      if (doIssue) { asm volatile("s_waitcnt vmcnt(8)" ::: "memory"); }
      else         { asm volatile("s_waitcnt vmcnt(0)" ::: "memory"); }
      __builtin_amdgcn_sched_barrier(0);
      expCvt(cur ^ 1);                      // raw t+1, delivered a full tile ago
      writeA(cur ^ 1);
    }
    asm volatile("s_waitcnt lgkmcnt(0)" ::: "memory");
    __builtin_amdgcn_sched_barrier(0);
    __builtin_amdgcn_s_barrier();
    __builtin_amdgcn_sched_barrier(0);
  };

  // ---- prologue: DMA tiles 0,1; convert tile 0 ----
  issueAr(0, 0);
  issueAr(1, 1);
  asm volatile("s_waitcnt vmcnt(8)" ::: "memory");   // tile0 landed; tile1 in flight
  __builtin_amdgcn_sched_barrier(0);
  __builtin_amdgcn_s_barrier();                       // Ar[0] visible to all waves
  __builtin_amdgcn_sched_barrier(0);
  expCvt(0);
  writeA(0);
  asm volatile("s_waitcnt lgkmcnt(0)" ::: "memory");
  __builtin_amdgcn_sched_barrier(0);
  __builtin_amdgcn_s_barrier();
  __builtin_amdgcn_sched_barrier(0);

  // ---- 16 K-tiles ----
  for (int i = 0; i < 7; ++i) {
    body(2 * i, true, true);
    body(2 * i + 1, true, true);
  }
  body(14, false, true);
  body(15, false, false);

  // ---- denominator: reduce k-quarter partials within each row-quad ----
  sacc += __shfl_xor(sacc, 1);
  sacc += __shfl_xor(sacc, 2);
  if (aq == 0) sden[(size_t)z * 8192 + mt * 64 + ar] = sacc;

  // ---- store unnormalized partial U as bf16: pbuf[z][row n][col b*128+d] ----
  unsigned short* po = pbuf + (size_t)z * 8192 * 512;
  #pragma unroll
  for (int mf = 0; mf < 4; ++mf)
    #pragma unroll
    for (int nf = 0; nf < 8; ++nf) {
      const int col = wn * 128 + nf * 16 + (lane & 15);
      #pragma unroll
      for (int q = 0; q < 4; ++q) {
        const int row = mt * 64 + mf * 16 + (lane >> 4) * 4 + q;
        po[(size_t)row * 512 + col] = f2bf(acc[mf][nf][q]);
      }
    }
}

// ---------------- fused LN2 + FFN: x1 = x + (sum_z U_z)/(sum_z S_z); h1 = LN(x1) -> As;
// out = x1 + relu(h1@w1+b1)@w2 + b2.  x1 parked f32 in As/W1c LDS after their last read.
#define SWZ16(ks, r) (((((ks) & 7) ^ ((r) & 7)) | ((ks) & 8)))
__global__ __launch_bounds__(512) void ln_ffn_kernel(const float* __restrict__ x,
                                                     const unsigned short* __restrict__ pbuf,
                                                     const float* __restrict__ sden,
                                                     const unsigned short* __restrict__ w1t,
                                                     const unsigned short* __restrict__ w2t,
                                                     const float* __restrict__ b1,
                                                     const float* __restrict__ b2,
                                                     float* __restrict__ out) {
  const int t = threadIdx.x, lane = t & 63, w = t >> 6;
  const int wr = w >> 1, wc = w & 1;   // 8 waves: 4x32 rows, 2x64 cols
  const int row0 = blockIdx.x * 128;
  __shared__ unsigned short As[128 * 128];
  __shared__ unsigned short W1c[128 * 128];
  __shared__ unsigned short W2c[128 * 128];
  __shared__ unsigned short Ts[128 * 128];

  auto stageW1 = [&](int hc) {
    #pragma unroll
    for (int i = 0; i < 4; ++i) {
      const int idx = i * 512 + t;
      const int row = idx >> 4, kc = idx & 15;
      const int kcs = (kc & 8) | ((kc & 7) ^ (row & 7));
      gld16(w1t + (size_t)(hc * 128 + row) * 128 + kcs * 8, W1c + (idx & ~63) * 8);
    }
  };
  auto stageW2 = [&](int hc) {
    #pragma unroll
    for (int i = 0; i < 4; ++i) {
      const int idx = i * 512 + t;
      const int row = idx >> 4, kc = idx & 15;
      const int kcs = (kc & 8) | ((kc & 7) ^ (row & 7));
      gld16(w2t + (size_t)row * 512 + hc * 128 + kcs * 8, W2c + (idx & ~63) * 8);
    }
  };

  stageW1(0); stageW2(0);

  // x1 = x + (sum U)/(sum S); LN over D=128 (4 threads/row); h1 -> As (bf16, swizzled)
  const int r = t >> 2, q = t & 3, c0 = q * 32;
  const int rowg = row0 + r;
  const int bb = rowg >> 13, nn = rowg & 8191;
  float xv[32];
  {
    const float den = sden[nn] + sden[8192 + nn] + sden[16384 + nn] + sden[24576 + nn];
    const float rinv = 1.f / den;
    const float* xp = x + (size_t)rowg * 128 + c0;
    #pragma unroll
    for (int j = 0; j < 8; ++j) {
      const float4 v4 = *(const float4*)(xp + 4 * j);
      xv[4 * j] = v4.x; xv[4 * j + 1] = v4.y; xv[4 * j + 2] = v4.z; xv[4 * j + 3] = v4.w;
    }
    #pragma unroll
    for (int z = 0; z < 4; ++z) {
      const unsigned short* pp = pbuf + ((size_t)z * 8192 + nn) * 512 + bb * 128 + c0;
      #pragma unroll
      for (int j = 0; j < 4; ++j) {
        const bh8 pv = *(const bh8*)(pp + 8 * j);
        #pragma unroll
        for (int e = 0; e < 8; ++e) xv[8 * j + e] += bflo2f((unsigned short)pv[e]) * rinv;
      }
    }
  }
  float s = 0.f, s2 = 0.f;
  #pragma unroll
  for (int j = 0; j < 32; ++j) { s += xv[j]; s2 += xv[j] * xv[j]; }
  s += __shfl_xor(s, 1); s2 += __shfl_xor(s2, 1);
  s += __shfl_xor(s, 2); s2 += __shfl_xor(s2, 2);
  const float mean = s * 0.0078125f;
  const float var = s2 * 0.0078125f - mean * mean;
  const float rstd = rsqrtf(var + 1e-5f);
  #pragma unroll
  for (int j = 0; j < 4; ++j) {
    const int g = q * 4 + j;
    bh8 pk;
    #pragma unroll
    for (int e = 0; e < 8; ++e) pk[e] = (short)f2bf((xv[8 * j + e] - mean) * rstd);
    *(bh8*)(As + r * 128 + SWZ16(g, r) * 8) = pk;
  }
  __syncthreads();  // As ready; W(0) staged

  fx4 accO[2][4];
  #pragma unroll
  for (int i = 0; i < 2; ++i)
    #pragma unroll
    for (int j = 0; j < 4; ++j) accO[i][j] = (fx4){0.f, 0.f, 0.f, 0.f};

  for (int hc = 0; hc < 4; ++hc) {
    if (hc > 0) stageW2(hc);  // overlaps GEMM1; drained at post-Ts barrier
    fx4 accT[2][4];
    #pragma unroll
    for (int i = 0; i < 2; ++i)
      #pragma unroll
      for (int j = 0; j < 4; ++j) accT[i][j] = (fx4){0.f, 0.f, 0.f, 0.f};
    #pragma unroll
    for (int kk = 0; kk < 4; ++kk) {
      const int ks = kk * 4 + (lane >> 4);
      bh8 af[2], bfr[4];
      #pragma unroll
      for (int f = 0; f < 2; ++f) {
        const int ra = wr * 32 + f * 16 + (lane & 15);
        af[f] = *(const bh8*)(As + ra * 128 + SWZ16(ks, ra) * 8);
      }
      #pragma unroll
      for (int f = 0; f < 4; ++f) {
        const int rb = wc * 64 + f * 16 + (lane & 15);
        bfr[f] = *(const bh8*)(W1c + rb * 128 + SWZ16(ks, rb) * 8);
      }
      #pragma unroll
      for (int fm = 0; fm < 2; ++fm)
        #pragma unroll
        for (int fn = 0; fn < 4; ++fn) accT[fm][fn] = MFMA(af[fm], bfr[fn], accT[fm][fn]);
    }
    // bias + relu -> Ts (bf16, swizzled)
    #pragma unroll
    for (int fm = 0; fm < 2; ++fm)
      #pragma unroll
      for (int fn = 0; fn < 4; ++fn) {
        const int col = wc * 64 + fn * 16 + (lane & 15);
        const float bv = b1[hc * 128 + col];
        const int c = col >> 3;
        #pragma unroll
        for (int qq = 0; qq < 4; ++qq) {
          const int row = wr * 32 + fm * 16 + (lane >> 4) * 4 + qq;
          float vv = accT[fm][fn][qq] + bv;
          vv = fmaxf(vv, 0.f);
          Ts[row * 128 + SWZ16(c, row) * 8 + (col & 7)] = f2bf(vv);
        }
      }
    __syncthreads();  // Ts ready; As/W1c GEMM1 reads done; W2c(hc) landed
    if (hc < 3) {
      stageW1(hc + 1);  // overlaps GEMM2; drained at loop-end barrier
    } else {
      // park x1 (f32) into As (rows 0-63) / W1c (rows 64-127) — both dead now
      float* dst = (r < 64) ? (float*)As + r * 128 + c0 : (float*)W1c + (r - 64) * 128 + c0;
      #pragma unroll
      for (int j = 0; j < 8; ++j)
        *(float4*)(dst + 4 * j) =
            (float4){xv[4 * j], xv[4 * j + 1], xv[4 * j + 2], xv[4 * j + 3]};
    }
    #pragma unroll
    for (int kk = 0; kk < 4; ++kk) {
      const int ks = kk * 4 + (lane >> 4);
      bh8 af[2], bfr[4];
      #pragma unroll
      for (int f = 0; f < 2; ++f) {
        const int ra = wr * 32 + f * 16 + (lane & 15);
        af[f] = *(const bh8*)(Ts + ra * 128 + SWZ16(ks, ra) * 8);
      }
      #pragma unroll
      for (int f = 0; f < 4; ++f) {
        const int rb = wc * 64 + f * 16 + (lane & 15);
        bfr[f] = *(const bh8*)(W2c + rb * 128 + SWZ16(ks, rb) * 8);
      }
      #pragma unroll
      for (int fm = 0; fm < 2; ++fm)
        #pragma unroll
        for (int fn = 0; fn < 4; ++fn) accO[fm][fn] = MFMA(af[fm], bfr[fn], accO[fm][fn]);
    }
    __syncthreads();
  }

  const float* x1a = (const float*)As;
  const float* x1b = (const float*)W1c;
  float* op = out + (size_t)row0 * 128;
  #pragma unroll
  for (int fm = 0; fm < 2; ++fm)
    #pragma unroll
    for (int fn = 0; fn < 4; ++fn) {
      const int col = wc * 64 + fn * 16 + (lane & 15);
      const float bv = b2[col];
      #pragma unroll
      for (int qq = 0; qq < 4; ++qq) {
        const int row = wr * 32 + fm * 16 + (lane >> 4) * 4 + qq;
        const float x1v = (row < 64) ? x1a[row * 128 + col] : x1b[(row - 64) * 128 + col];
        op[row * 128 + col] = x1v + accO[fm][fn][qq] + bv;
      }
    }
}

extern "C" void kernel_launch(void* const* d_in, const int* in_sizes, int n_in,
                              void* d_out, int out_size, void* d_ws, size_t ws_size,
                              hipStream_t stream) {
  const float* x   = (const float*)d_in[0];
  const float* adj = (const float*)d_in[1];
  const float* w1  = (const float*)d_in[4];
  const float* b1  = (const float*)d_in[5];
  const float* w2  = (const float*)d_in[6];
  const float* b2  = (const float*)d_in[7];
  float* out = (float*)d_out;

  char* p = (char*)d_ws;
  unsigned short* w1t  = (unsigned short*)p; p += (size_t)512 * 128 * 2;
  unsigned short* w2t  = (unsigned short*)p; p += (size_t)128 * 512 * 2;
  unsigned char*  htf  = (unsigned char*)p;  p += (size_t)4 * 128 * 8192;
  unsigned short* pbuf = (unsigned short*)p; p += (size_t)4 * 8192 * 512 * 2;
  float*          sden = (float*)p;          p += (size_t)4 * 8192 * 4;

  transpose_weights<<<256, 256, 0, stream>>>(w1, w2, w1t, w2t);
  ln1_transpose<<<dim3(128, 4), 256, 0, stream>>>(x, htf);
  fused_attn<<<dim3(128, 4), 256, 0, stream>>>(adj, htf, pbuf, sden);
  ln_ffn_kernel<<<256, 512, 0, stream>>>(x, pbuf, sden, w1t, w2t, b1, b2, out);
}